// Round 12
// baseline (168.995 us; speedup 1.0000x reference)
//
#include <hip/hip_runtime.h>
#include <math.h>

#define BATCH 32
#define HH 512
#define WW 512
#define NC 32        // cells per side
#define NORI 6
#define CH 262144    // HH*WW channel stride (floats)
#define GRAYSZ 262144

// ---- round-5-verbatim numpy downstream (cold path, ONE inline copy) ----
__device__ __forceinline__ int bin_of(float a) {
    const float deg = __fmul_rn(a, 57.29577951308232f);
    float m = fmodf(deg, 180.0f);
    if (m < 0.0f) m = __fadd_rn(m, 180.0f);
    const int b = (int)floorf(__fdiv_rn(m, 30.0f));
    return min(max(b, 0), NORI - 1);
}
__device__ __forceinline__ float ulp_step(float x, int k) {
    const int i = __float_as_int(x);
    int key = (i >= 0) ? i : -(i & 0x7FFFFFFF);
    key += k;
    const int r = (key >= 0) ? key : (int)(0x80000000u | (unsigned)(-key));
    return __int_as_float(r);
}
__device__ __forceinline__ void deposit(float acc[NORI], int bin, float val) {
#pragma unroll
    for (int o = 0; o < NORI; ++o) acc[o] += (bin == o) ? val : 0.0f;
}
// (0.299*R + 0.587*G) + 0.114*B, f32, no FMA contraction
__device__ __forceinline__ float gray_comb(float r, float g, float b) {
    return __fadd_rn(__fadd_rn(__fmul_rn(0.299f, r), __fmul_rn(0.587f, g)),
                     __fmul_rn(0.114f, b));
}

// Pass 1: RGB -> gray, copy-shaped pure streaming (the only access pattern
// measured at full HBM rate on this part: grid-stride dwordx4 in/out).
__global__ __launch_bounds__(256) void gray_kernel(const float* __restrict__ x,
                                                   float* __restrict__ gray) {
    int i = blockIdx.x * 256 + threadIdx.x;        // 524288 threads
    const int stride = 2048 * 256;
#pragma unroll
    for (int k = 0; k < 4; ++k, i += stride) {     // 4 x 524288 = 2M float4
        const int img = i >> 16;                   // / (GRAYSZ/4)
        const int off = (i & 0xFFFF) << 2;
        const float* base = x + (size_t)img * 3 * GRAYSZ + off;
        const float4 r = *(const float4*)(base);
        const float4 g = *(const float4*)(base + CH);
        const float4 b = *(const float4*)(base + 2 * CH);
        float4 o;
        o.x = gray_comb(r.x, g.x, b.x);
        o.y = gray_comb(r.y, g.y, b.y);
        o.z = gray_comb(r.z, g.z, b.z);
        o.w = gray_comb(r.w, g.w, b.w);
        *(float4*)(gray + (size_t)img * GRAYSZ + off) = o;
    }
}

__device__ __forceinline__ void hot_pixel(float gy, float gx, int bitk,
                                          float acc[NORI], unsigned& ambmask) {
    const float mag = __fsqrt_rn(__fmaf_rn(gy, gy, __fmul_rn(gx, gx)));
    // canonicalize to theta in [0,180)
    const bool neg = gy < 0.0f;
    const float cy = fabsf(gy);
    const float cx = neg ? -gx : gx;
    // t_i ~ sin(theta - alpha_i), alpha = 30,60,90,120,150 (shared products)
    const float pa = __fmul_rn(cy, 0.86602540378443864676f);
    const float pb = __fmul_rn(cx, 0.5f);
    const float pc = __fmul_rn(cy, 0.5f);
    const float pd = __fmul_rn(cx, 0.86602540378443864676f);
    const float t1 = __fsub_rn(pa, pb);
    const float t2 = __fsub_rn(pc, pd);
    const float t3 = -cx;
    const float t4 = -__fadd_rn(pc, pd);
    const float t5 = -__fadd_rn(pa, pb);
    int bin = (t1 >= 0.0f) + (t2 >= 0.0f) + (t3 >= 0.0f) +
              (t4 >= 0.0f) + (t5 >= 0.0f);
    const float s = __fmul_rn(mag, 1e-5f);
    const float mn = fminf(fminf(fminf(fabsf(t1), fabsf(t2)),
                                 fminf(fabsf(t3), fabsf(t4))), fabsf(t5));
    bool amb = (mn < s) || (cx < 0.0f && cy < s);   // incl. wrap at 180
    if (gy == 0.0f) { bin = 0; amb = false; }       // deterministic (r3/r5)
    else if (gx == 0.0f) { bin = 3; amb = false; }
    ambmask |= amb ? (1u << bitk) : 0u;
    deposit(acc, bin, amb ? 0.0f : mag);
}

// Pass 2: cells from the gray plane (r11 structure, 1/3 the bytes, gray is
// L2/L3-resident). Lane = 4 cols; wave = 256 cols x 4 rows; block = 16 rows.
__global__ __launch_bounds__(256) void hog_cells_kernel(const float* __restrict__ gray,
                                                        float* __restrict__ cells) {
    const int b = blockIdx.z;
    const int tid = threadIdx.x;
    const int wave = tid >> 6, lane = tid & 63;
    const int by = blockIdx.y;              // cell row
    const int R0 = by * 16 + wave * 4;      // this wave's first output row
    const int C0 = blockIdx.x * 256;
    const int c0 = C0 + lane * 4;
    const float* gp = gray + (size_t)b * GRAYSZ;

    __shared__ float hist[16][NORI];
    if (tid < 16 * NORI) ((float*)hist)[tid] = 0.0f;
    __syncthreads();

    // single halo column per wave: left block needs abs col 256 (lane 63),
    // right block needs abs col 255 (lane 0). Image borders give gx=0 instead.
    const bool left_blk = (blockIdx.x == 0);
    const int hc = left_blk ? 256 : 255;
    const bool is_h = (lane == (left_blk ? 63 : 0));

    int roff[6];
#pragma unroll
    for (int i = 0; i < 6; ++i)
        roff[i] = min(max(R0 - 1 + i, 0), HH - 1) * WW;

    // burst: 6 dwordx4 + (edge lanes) 6 scalar halo loads
    float4 g[6];
#pragma unroll
    for (int i = 0; i < 6; ++i)
        g[i] = *(const float4*)(gp + roff[i] + c0);
    float hrow[6];
#pragma unroll
    for (int i = 0; i < 6; ++i)
        hrow[i] = is_h ? gp[roff[i] + hc] : 0.0f;

    float acc[NORI] = {0, 0, 0, 0, 0, 0};
    unsigned ambmask = 0;

#pragma unroll
    for (int k = 0; k < 4; ++k) {
        const int r = R0 + k;
        const bool row_ok = (r >= 1) && (r < HH - 1);
        const float4 gt = g[k], gc = g[k + 1], gb = g[k + 2];
        const float gy0 = row_ok ? __fsub_rn(gb.x, gt.x) : 0.0f;
        const float gy1 = row_ok ? __fsub_rn(gb.y, gt.y) : 0.0f;
        const float gy2 = row_ok ? __fsub_rn(gb.z, gt.z) : 0.0f;
        const float gy3 = row_ok ? __fsub_rn(gb.w, gt.w) : 0.0f;

        float left  = __shfl(gc.w, (lane + 63) & 63);
        float right = __shfl(gc.x, (lane + 1) & 63);
        if (is_h) { if (left_blk) right = hrow[k + 1]; else left = hrow[k + 1]; }

        float gx0 = __fsub_rn(gc.y, left);
        const float gx1 = __fsub_rn(gc.z, gc.x);
        const float gx2 = __fsub_rn(gc.w, gc.y);
        float gx3 = __fsub_rn(right, gc.z);
        if (c0 == 0) gx0 = 0.0f;             // image left border
        if (c0 + 3 == WW - 1) gx3 = 0.0f;    // image right border

        hot_pixel(gy0, gx0, 4 * k + 0, acc, ambmask);
        hot_pixel(gy1, gx1, 4 * k + 1, acc, ambmask);
        hot_pixel(gy2, gx2, 4 * k + 2, acc, ambmask);
        hot_pixel(gy3, gx3, 4 * k + 3, acc, ambmask);
    }

    // cold phase: rare. amb pixels are interior with gy!=0 && gx!=0;
    // re-read the SAME stored gray values -> bitwise identical.
    if (__any(ambmask != 0)) {
        unsigned m = ambmask;
        while (m) {
            const int bit = __builtin_ctz(m);
            m &= m - 1;
            const int r = R0 + (bit >> 2);
            const int c = c0 + (bit & 3);
            const int off = r * WW + c;
            const float gy = __fsub_rn(gp[off + WW], gp[off - WW]);
            const float gx = __fsub_rn(gp[off + 1], gp[off - 1]);
            const float mag = __fsqrt_rn(__fmaf_rn(gy, gy, __fmul_rn(gx, gx)));
            const float a = atan2f(gy, gx);
            const int bl = bin_of(ulp_step(a, -2));
            const int bh = bin_of(ulp_step(a, +2));
            if (bl == bh) {
                deposit(acc, bl, mag);
            } else {
                const int b0 = bin_of(a);
                const int bo = (b0 == bl) ? bh : bl;
                deposit(acc, b0, __fmul_rn(mag, 0.65f));
                deposit(acc, bo, __fmul_rn(mag, 0.35f));
            }
        }
    }

    // reduce the 4 lanes of each cell (16 cols = lanes 4c..4c+3)
#pragma unroll
    for (int o = 0; o < NORI; ++o) {
        float v = acc[o];
        v += __shfl_xor(v, 1);
        v += __shfl_xor(v, 2);
        acc[o] = v;
    }
    if ((lane & 3) == 0) {
        const int cell = lane >> 2;
#pragma unroll
        for (int o = 0; o < NORI; ++o) atomicAdd(&hist[cell][o], acc[o]);
    }
    __syncthreads();
    if (tid < 96) {
        const int cell = tid / 6, o = tid - cell * 6;
        cells[(((size_t)b * NC + by) * NC + ((C0 >> 4) + cell)) * NORI + o] =
            hist[cell][o] * (1.0f / 256.0f);
    }
}

// One thread per (b, block_row, block_col): float2 loads, L2-Hys normalize.
__global__ __launch_bounds__(256) void hog_norm_kernel(const float* __restrict__ cells,
                                                       float* __restrict__ out) {
    const int idx = blockIdx.x * 256 + threadIdx.x;
    const int total = BATCH * 31 * 31;
    if (idx >= total) return;
    const int bc = idx % 31;
    const int t = idx / 31;
    const int br = t % 31;
    const int b = t / 31;

    const float* cb = cells + (size_t)b * NC * NC * NORI;
    const float2* p0 = (const float2*)(cb + ((br) * NC + bc) * NORI);
    const float2* p1 = (const float2*)(cb + ((br + 1) * NC + bc) * NORI);
    float v[24];
#pragma unroll
    for (int q = 0; q < 6; ++q) {
        const float2 r0 = p0[q], r1 = p1[q];
        v[2 * q] = r0.x; v[2 * q + 1] = r0.y;
        v[12 + 2 * q] = r1.x; v[12 + 2 * q + 1] = r1.y;
    }
    float ss = 0.0f;
#pragma unroll
    for (int k = 0; k < 24; ++k) ss = __fadd_rn(ss, __fmul_rn(v[k], v[k]));
    const float n1 = __fsqrt_rn(__fadd_rn(ss, 1e-10f));  // EPS^2, EPS=1e-5
    float ss2 = 0.0f;
#pragma unroll
    for (int k = 0; k < 24; ++k) {
        v[k] = fminf(__fdiv_rn(v[k], n1), 0.2f);
        ss2 = __fadd_rn(ss2, __fmul_rn(v[k], v[k]));
    }
    const float n2 = __fsqrt_rn(__fadd_rn(ss2, 1e-10f));
    float* op = out + (size_t)idx * 24;
#pragma unroll
    for (int k = 0; k < 24; ++k) op[k] = __fdiv_rn(v[k], n2);
}

extern "C" void kernel_launch(void* const* d_in, const int* in_sizes, int n_in,
                              void* d_out, int out_size, void* d_ws, size_t ws_size,
                              hipStream_t stream) {
    const float* x = (const float*)d_in[0];
    float* out = (float*)d_out;
    float* cells = (float*)d_ws;                        // 3 MB
    float* gray = (float*)d_ws + (1 << 20);             // +4 MB offset, 32 MB

    gray_kernel<<<2048, 256, 0, stream>>>(x, gray);

    dim3 g1(2, NC, BATCH), b1(256);
    hog_cells_kernel<<<g1, b1, 0, stream>>>(gray, cells);

    const int total = BATCH * 31 * 31;
    hog_norm_kernel<<<(total + 255) / 256, 256, 0, stream>>>(cells, out);
}

// Round 13
// 154.113 us; speedup vs baseline: 1.0966x; 1.0966x over previous
//
#include <hip/hip_runtime.h>
#include <math.h>

#define BATCH 32
#define HH 512
#define WW 512
#define NC 32        // cells per side
#define NORI 6
#define CH 262144    // HH*WW channel stride (floats)

// ---- round-5-verbatim numpy downstream (cold path, ONE inline copy) ----
__device__ __forceinline__ int bin_of(float a) {
    const float deg = __fmul_rn(a, 57.29577951308232f);
    float m = fmodf(deg, 180.0f);
    if (m < 0.0f) m = __fadd_rn(m, 180.0f);
    const int b = (int)floorf(__fdiv_rn(m, 30.0f));
    return min(max(b, 0), NORI - 1);
}
__device__ __forceinline__ float ulp_step(float x, int k) {
    const int i = __float_as_int(x);
    int key = (i >= 0) ? i : -(i & 0x7FFFFFFF);
    key += k;
    const int r = (key >= 0) ? key : (int)(0x80000000u | (unsigned)(-key));
    return __int_as_float(r);
}
__device__ __forceinline__ void deposit(float acc[NORI], int bin, float val) {
#pragma unroll
    for (int o = 0; o < NORI; ++o) acc[o] += (bin == o) ? val : 0.0f;
}
// (0.299*R + 0.587*G) + 0.114*B, f32, no FMA contraction
__device__ __forceinline__ float gray_comb(float r, float g, float b) {
    return __fadd_rn(__fadd_rn(__fmul_rn(0.299f, r), __fmul_rn(0.587f, g)),
                     __fmul_rn(0.114f, b));
}
__device__ __forceinline__ float gray_i(const float* __restrict__ img, int off) {
    return gray_comb(img[off], img[off + CH], img[off + 2 * CH]);
}
__device__ __forceinline__ float4 gray4(const float* __restrict__ img, int off) {
    const float4 r = *(const float4*)(img + off);
    const float4 g = *(const float4*)(img + off + CH);
    const float4 b = *(const float4*)(img + off + 2 * CH);
    float4 o;
    o.x = gray_comb(r.x, g.x, b.x);
    o.y = gray_comb(r.y, g.y, b.y);
    o.z = gray_comb(r.z, g.z, b.z);
    o.w = gray_comb(r.w, g.w, b.w);
    return o;
}

__device__ __forceinline__ void hot_pixel(float gy, float gx, int bitk,
                                          float acc[NORI], unsigned& ambmask) {
    const float mag = __fsqrt_rn(__fmaf_rn(gy, gy, __fmul_rn(gx, gx)));
    // canonicalize to theta in [0,180)
    const bool neg = gy < 0.0f;
    const float cy = fabsf(gy);
    const float cx = neg ? -gx : gx;
    // t_i ~ sin(theta - alpha_i), alpha = 30,60,90,120,150 (shared products)
    const float pa = __fmul_rn(cy, 0.86602540378443864676f);
    const float pb = __fmul_rn(cx, 0.5f);
    const float pc = __fmul_rn(cy, 0.5f);
    const float pd = __fmul_rn(cx, 0.86602540378443864676f);
    const float t1 = __fsub_rn(pa, pb);
    const float t2 = __fsub_rn(pc, pd);
    const float t3 = -cx;
    const float t4 = -__fadd_rn(pc, pd);
    const float t5 = -__fadd_rn(pa, pb);
    int bin = (t1 >= 0.0f) + (t2 >= 0.0f) + (t3 >= 0.0f) +
              (t4 >= 0.0f) + (t5 >= 0.0f);
    const float s = __fmul_rn(mag, 1e-5f);
    const float mn = fminf(fminf(fminf(fabsf(t1), fabsf(t2)),
                                 fminf(fabsf(t3), fabsf(t4))), fabsf(t5));
    bool amb = (mn < s) || (cx < 0.0f && cy < s);   // incl. wrap at 180
    if (gy == 0.0f) { bin = 0; amb = false; }       // deterministic (r3/r5)
    else if (gx == 0.0f) { bin = 3; amb = false; }
    ambmask |= amb ? (1u << bitk) : 0u;
    deposit(acc, bin, amb ? 0.0f : mag);
}

// Lane = 4 adjacent columns (float4 channel loads); wave = 256 cols x 4 rows.
// FULLY wave-independent: no LDS, no atomics, no __syncthreads. Each wave
// writes per-subrow partial histograms; hog_norm sums the 4 subrows.
// part[b][cellr][cellc][sub(4)][ori(6)] -> 24 contiguous floats per cell.
__global__ __launch_bounds__(256) void hog_cells_kernel(const float* __restrict__ x,
                                                        float* __restrict__ part) {
    const int b = blockIdx.z;
    const int tid = threadIdx.x;
    const int wave = tid >> 6, lane = tid & 63;
    const int by = blockIdx.y;              // cell row
    const int R0 = by * 16 + wave * 4;      // this wave's first pixel row
    const int C0 = blockIdx.x * 256;
    const int c0 = C0 + lane * 4;
    const float* img = x + (size_t)b * 3 * HH * WW;

    // single halo column per wave: left block needs abs col 256 (lane 63),
    // right block needs abs col 255 (lane 0). Image borders give gx=0 instead.
    const bool left_blk = (blockIdx.x == 0);
    const int hc = left_blk ? 256 : 255;
    const bool is_h = (lane == (left_blk ? 63 : 0));

    float4 gm1 = gray4(img, max(R0 - 1, 0) * WW + c0);
    float4 g0  = gray4(img, R0 * WW + c0);
    float hcur = is_h ? gray_i(img, R0 * WW + hc) : 0.0f;

    float acc[NORI] = {0, 0, 0, 0, 0, 0};
    unsigned ambmask = 0;

#pragma unroll
    for (int k = 0; k < 4; ++k) {
        const int r = R0 + k;
        const int rn = min(r + 1, HH - 1);
        const float4 gp1 = gray4(img, rn * WW + c0);
        const float hnext = is_h ? gray_i(img, rn * WW + hc) : 0.0f;

        const bool row_ok = (r >= 1) && (r < HH - 1);
        const float gy0 = row_ok ? __fsub_rn(gp1.x, gm1.x) : 0.0f;
        const float gy1 = row_ok ? __fsub_rn(gp1.y, gm1.y) : 0.0f;
        const float gy2 = row_ok ? __fsub_rn(gp1.z, gm1.z) : 0.0f;
        const float gy3 = row_ok ? __fsub_rn(gp1.w, gm1.w) : 0.0f;

        float left  = __shfl(g0.w, (lane + 63) & 63);
        float right = __shfl(g0.x, (lane + 1) & 63);
        if (is_h) { if (left_blk) right = hcur; else left = hcur; }

        float gx0 = __fsub_rn(g0.y, left);
        const float gx1 = __fsub_rn(g0.z, g0.x);
        const float gx2 = __fsub_rn(g0.w, g0.y);
        float gx3 = __fsub_rn(right, g0.z);
        if (c0 == 0) gx0 = 0.0f;             // image left border
        if (c0 + 3 == WW - 1) gx3 = 0.0f;    // image right border

        hot_pixel(gy0, gx0, 4 * k + 0, acc, ambmask);
        hot_pixel(gy1, gx1, 4 * k + 1, acc, ambmask);
        hot_pixel(gy2, gx2, 4 * k + 2, acc, ambmask);
        hot_pixel(gy3, gx3, 4 * k + 3, acc, ambmask);

        gm1 = g0; g0 = gp1; hcur = hnext;
    }

    // cold phase: rare. amb pixels are interior with gy!=0 && gx!=0;
    // recompute bitwise-identically from global memory.
    if (__any(ambmask != 0)) {
        unsigned m = ambmask;
        while (m) {
            const int bit = __builtin_ctz(m);
            m &= m - 1;
            const int r = R0 + (bit >> 2);
            const int c = c0 + (bit & 3);
            const int off = r * WW + c;
            const float gy = __fsub_rn(gray_i(img, off + WW), gray_i(img, off - WW));
            const float gx = __fsub_rn(gray_i(img, off + 1), gray_i(img, off - 1));
            const float mag = __fsqrt_rn(__fmaf_rn(gy, gy, __fmul_rn(gx, gx)));
            const float a = atan2f(gy, gx);
            const int bl = bin_of(ulp_step(a, -2));
            const int bh = bin_of(ulp_step(a, +2));
            if (bl == bh) {
                deposit(acc, bl, mag);
            } else {
                const int b0 = bin_of(a);
                const int bo = (b0 == bl) ? bh : bl;
                deposit(acc, b0, __fmul_rn(mag, 0.65f));
                deposit(acc, bo, __fmul_rn(mag, 0.35f));
            }
        }
    }

    // reduce the 4 lanes of each cell (16 cols = lanes 4c..4c+3)
#pragma unroll
    for (int o = 0; o < NORI; ++o) {
        float v = acc[o];
        v += __shfl_xor(v, 1);
        v += __shfl_xor(v, 2);
        acc[o] = v;
    }
    if ((lane & 3) == 0) {
        const int cell = lane >> 2;                    // 0..15 within block
        const int cc = (C0 >> 4) + cell;               // global cell col
        float* pp = part + ((((size_t)b * NC + by) * NC + cc) * 4 + wave) * NORI;
#pragma unroll
        for (int o = 0; o < NORI; ++o) pp[o] = acc[o];
    }
}

// One thread per (b, block_row, block_col): sum 4 subrow partials per cell
// (6 x float4 contiguous loads), then L2-Hys normalize.
__global__ __launch_bounds__(256) void hog_norm_kernel(const float* __restrict__ part,
                                                       float* __restrict__ out) {
    const int idx = blockIdx.x * 256 + threadIdx.x;
    const int total = BATCH * 31 * 31;
    if (idx >= total) return;
    const int bc = idx % 31;
    const int t = idx / 31;
    const int br = t % 31;
    const int b = t / 31;

    float v[24];
#pragma unroll
    for (int i = 0; i < 2; ++i)
#pragma unroll
        for (int j = 0; j < 2; ++j) {
            const float* pp = part + ((((size_t)b * NC + (br + i)) * NC + (bc + j)) * 4) * NORI;
            float s[NORI];
#pragma unroll
            for (int o = 0; o < NORI; ++o)
                s[o] = ((pp[o] + pp[6 + o]) + pp[12 + o]) + pp[18 + o];
#pragma unroll
            for (int o = 0; o < NORI; ++o)
                v[(i * 2 + j) * NORI + o] = s[o] * (1.0f / 256.0f);
        }

    float ss = 0.0f;
#pragma unroll
    for (int k = 0; k < 24; ++k) ss = __fadd_rn(ss, __fmul_rn(v[k], v[k]));
    const float n1 = __fsqrt_rn(__fadd_rn(ss, 1e-10f));  // EPS^2, EPS=1e-5
    float ss2 = 0.0f;
#pragma unroll
    for (int k = 0; k < 24; ++k) {
        v[k] = fminf(__fdiv_rn(v[k], n1), 0.2f);
        ss2 = __fadd_rn(ss2, __fmul_rn(v[k], v[k]));
    }
    const float n2 = __fsqrt_rn(__fadd_rn(ss2, 1e-10f));
    float* op = out + (size_t)idx * 24;
#pragma unroll
    for (int k = 0; k < 24; ++k) op[k] = __fdiv_rn(v[k], n2);
}

extern "C" void kernel_launch(void* const* d_in, const int* in_sizes, int n_in,
                              void* d_out, int out_size, void* d_ws, size_t ws_size,
                              hipStream_t stream) {
    const float* x = (const float*)d_in[0];
    float* out = (float*)d_out;
    float* part = (float*)d_ws;   // BATCH*32*32*4*6 floats = 12 MB

    dim3 g1(2, NC, BATCH), b1(256);
    hog_cells_kernel<<<g1, b1, 0, stream>>>(x, part);

    const int total = BATCH * 31 * 31;
    hog_norm_kernel<<<(total + 255) / 256, 256, 0, stream>>>(part, out);
}